// Round 10
// baseline (32.402 us; speedup 1.0000x reference)
//
#include <hip/hip_runtime.h>

// QTLayer via tensor-train composition, bf16 tables, 4 samples/thread:
//   out[b] = core0[s0]·M1(s1)·M2(s2)·c3(a) = w[s0*256+s1] · u[s2*64+a]
// MEASUREMENT ROUND: identical to the 21.3us best-known (R5 structure,
// plain gathers, nt streams) PLUS a duplicate qt_main4 launch (idempotent:
// rewrites the same outputs). Delta vs 21.3 = steady-state qt_main time,
// immune to fixed graph/replay overhead. This attributes the 21.3 split
// between {make_tables + node gap} and {qt_main} since rocprof top-5 is
// polluted by harness poison-fills.
// Established: gather phase is scattered-request service-rate bound
// (ILP x4 neutral, occupancy-shape neutral, L1-bypass neutral, nt hurt);
// request count (2/sample) is the structural floor.

#define QT_B (1 << 20)
#define NS 256
#define NA 64

#define W_ROWS (NS * NS)   // 65536
#define U_ROWS (NS * NA)   // 16384
#define MAIN_BLOCKS (QT_B / 4 / 256)   // 1024

typedef int          vint4   __attribute__((ext_vector_type(4)));
typedef unsigned int vuint4  __attribute__((ext_vector_type(4)));
typedef float        vfloat4 __attribute__((ext_vector_type(4)));

__device__ __forceinline__ unsigned short f2bf(float x) {
    unsigned int u = __float_as_uint(x);
    unsigned int r = (u + 0x7fffu + ((u >> 16) & 1u)) >> 16;  // RNE
    return (unsigned short)r;
}

__device__ __forceinline__ float bf_lo(unsigned int u) {
    return __uint_as_float(u << 16);
}
__device__ __forceinline__ float bf_hi(unsigned int u) {
    return __uint_as_float(u & 0xffff0000u);
}

__device__ __forceinline__ float dot8bf(vuint4 wv, vuint4 uv) {
    float acc;
    acc = bf_lo(wv.x) * bf_lo(uv.x);
    acc = fmaf(bf_hi(wv.x), bf_hi(uv.x), acc);
    acc = fmaf(bf_lo(wv.y), bf_lo(uv.y), acc);
    acc = fmaf(bf_hi(wv.y), bf_hi(uv.y), acc);
    acc = fmaf(bf_lo(wv.z), bf_lo(uv.z), acc);
    acc = fmaf(bf_hi(wv.z), bf_hi(uv.z), acc);
    acc = fmaf(bf_lo(wv.w), bf_lo(uv.w), acc);
    acc = fmaf(bf_hi(wv.w), bf_hi(uv.w), acc);
    return acc;
}

__device__ __forceinline__ vuint4 pack8bf(const float acc[8]) {
    vuint4 p;
    p.x = (unsigned)f2bf(acc[0]) | ((unsigned)f2bf(acc[1]) << 16);
    p.y = (unsigned)f2bf(acc[2]) | ((unsigned)f2bf(acc[3]) << 16);
    p.z = (unsigned)f2bf(acc[4]) | ((unsigned)f2bf(acc[5]) << 16);
    p.w = (unsigned)f2bf(acc[6]) | ((unsigned)f2bf(acc[7]) << 16);
    return p;
}

__device__ __forceinline__ void build_w_row(
    const float* __restrict__ core0, const float* __restrict__ core1,
    int s0, int s1, vuint4* __restrict__ wbf)
{
    float acc[8] = {0.f, 0.f, 0.f, 0.f, 0.f, 0.f, 0.f, 0.f};
#pragma unroll
    for (int r = 0; r < 8; ++r) {
        const float c = core0[s0 * 8 + r];
        const float* row = core1 + (r * (NS * 8) + s1 * 8);
        const float4 lo = *(const float4*)row;
        const float4 hi = *(const float4*)(row + 4);
        acc[0] = fmaf(c, lo.x, acc[0]);
        acc[1] = fmaf(c, lo.y, acc[1]);
        acc[2] = fmaf(c, lo.z, acc[2]);
        acc[3] = fmaf(c, lo.w, acc[3]);
        acc[4] = fmaf(c, hi.x, acc[4]);
        acc[5] = fmaf(c, hi.y, acc[5]);
        acc[6] = fmaf(c, hi.z, acc[6]);
        acc[7] = fmaf(c, hi.w, acc[7]);
    }
    wbf[s0 * NS + s1] = pack8bf(acc);
}

__device__ __forceinline__ void build_u_row(
    const float* __restrict__ core2, const float* __restrict__ core3,
    int q, vuint4* __restrict__ ubf)
{
    const int s2 = q >> 6;
    const int a  = q & (NA - 1);
    float c3[8];
#pragma unroll
    for (int s = 0; s < 8; ++s) c3[s] = core3[s * NA + a];
    float acc[8];
#pragma unroll
    for (int r = 0; r < 8; ++r) {
        const float* row = core2 + (r * (NS * 8) + s2 * 8);
        const float4 lo = *(const float4*)row;
        const float4 hi = *(const float4*)(row + 4);
        acc[r] = lo.x * c3[0] + lo.y * c3[1] + lo.z * c3[2] + lo.w * c3[3] +
                 hi.x * c3[4] + hi.y * c3[5] + hi.z * c3[6] + hi.w * c3[7];
    }
    ubf[q] = pack8bf(acc);
}

// ---------- precompute: blocks [0,256) build w, [256,320) build u
__global__ __launch_bounds__(256) void qt_make_tables(
    const float* __restrict__ core0,
    const float* __restrict__ core1,
    const float* __restrict__ core2,
    const float* __restrict__ core3,
    vuint4* __restrict__ wbf,
    vuint4* __restrict__ ubf)
{
    const int blk = blockIdx.x;
    if (blk < NS) {
        build_w_row(core0, core1, blk, threadIdx.x, wbf);
    } else {
        build_u_row(core2, core3, (blk - NS) * 256 + threadIdx.x, ubf);
    }
}

// ---------- main: 4 samples/thread, plain gathers (best-known form)
__global__ __launch_bounds__(256) void qt_main4(
    const vint4* __restrict__ states4,
    const vint4* __restrict__ actions4,
    const vuint4* __restrict__ wbf,
    const vuint4* __restrict__ ubf,
    vfloat4* __restrict__ out4)
{
    const int t = blockIdx.x * blockDim.x + threadIdx.x;  // t < B/4

    const vint4 sa = __builtin_nontemporal_load(&states4[3 * t + 0]);
    const vint4 sb = __builtin_nontemporal_load(&states4[3 * t + 1]);
    const vint4 sc = __builtin_nontemporal_load(&states4[3 * t + 2]);
    const vint4 ac = __builtin_nontemporal_load(&actions4[t]);

    // sample 0: (sa.x, sa.y, sa.z, ac.x)
    // sample 1: (sa.w, sb.x, sb.y, ac.y)
    // sample 2: (sb.z, sb.w, sc.x, ac.z)
    // sample 3: (sc.y, sc.z, sc.w, ac.w)
    const vuint4 w0 = wbf[sa.x * NS + sa.y];
    const vuint4 u0 = ubf[sa.z * NA + ac.x];
    const vuint4 w1 = wbf[sa.w * NS + sb.x];
    const vuint4 u1 = ubf[sb.y * NA + ac.y];
    const vuint4 w2 = wbf[sb.z * NS + sb.w];
    const vuint4 u2 = ubf[sc.x * NA + ac.z];
    const vuint4 w3 = wbf[sc.y * NS + sc.z];
    const vuint4 u3 = ubf[sc.w * NA + ac.w];

    vfloat4 o;
    o.x = dot8bf(w0, u0);
    o.y = dot8bf(w1, u1);
    o.z = dot8bf(w2, u2);
    o.w = dot8bf(w3, u3);

    __builtin_nontemporal_store(o, &out4[t]);
}

// ---------- fallback (round-1 kernel) if ws is too small
__global__ __launch_bounds__(256) void qt_direct(
    const int* __restrict__ states,
    const int* __restrict__ actions,
    const float* __restrict__ core0,
    const float* __restrict__ core1,
    const float* __restrict__ core2,
    const float* __restrict__ core3,
    float* __restrict__ out)
{
    const int b = blockIdx.x * blockDim.x + threadIdx.x;
    if (b >= QT_B) return;

    const int s0 = states[3 * b + 0];
    const int s1 = states[3 * b + 1];
    const int s2 = states[3 * b + 2];
    const int a  = actions[b];

    const float4 v0lo = *(const float4*)(core0 + s0 * 8);
    const float4 v0hi = *(const float4*)(core0 + s0 * 8 + 4);
    float v0[8] = {v0lo.x, v0lo.y, v0lo.z, v0lo.w,
                   v0hi.x, v0hi.y, v0hi.z, v0hi.w};

    float v1[8] = {0.f};
#pragma unroll
    for (int r = 0; r < 8; ++r) {
        const float* row = core1 + (r * (NS * 8) + s1 * 8);
        const float4 lo = *(const float4*)row;
        const float4 hi = *(const float4*)(row + 4);
        const float c = v0[r];
        v1[0] = fmaf(c, lo.x, v1[0]); v1[1] = fmaf(c, lo.y, v1[1]);
        v1[2] = fmaf(c, lo.z, v1[2]); v1[3] = fmaf(c, lo.w, v1[3]);
        v1[4] = fmaf(c, hi.x, v1[4]); v1[5] = fmaf(c, hi.y, v1[5]);
        v1[6] = fmaf(c, hi.z, v1[6]); v1[7] = fmaf(c, hi.w, v1[7]);
    }

    float v2[8] = {0.f};
#pragma unroll
    for (int r = 0; r < 8; ++r) {
        const float* row = core2 + (r * (NS * 8) + s2 * 8);
        const float4 lo = *(const float4*)row;
        const float4 hi = *(const float4*)(row + 4);
        const float c = v1[r];
        v2[0] = fmaf(c, lo.x, v2[0]); v2[1] = fmaf(c, lo.y, v2[1]);
        v2[2] = fmaf(c, lo.z, v2[2]); v2[3] = fmaf(c, lo.w, v2[3]);
        v2[4] = fmaf(c, hi.x, v2[4]); v2[5] = fmaf(c, hi.y, v2[5]);
        v2[6] = fmaf(c, hi.z, v2[6]); v2[7] = fmaf(c, hi.w, v2[7]);
    }

    float acc = 0.f;
#pragma unroll
    for (int r = 0; r < 8; ++r) acc = fmaf(v2[r], core3[r * NA + a], acc);
    out[b] = acc;
}

extern "C" void kernel_launch(void* const* d_in, const int* in_sizes, int n_in,
                              void* d_out, int out_size, void* d_ws, size_t ws_size,
                              hipStream_t stream) {
    const int*   states  = (const int*)d_in[0];
    const int*   actions = (const int*)d_in[1];
    const float* core0   = (const float*)d_in[2];
    const float* core1   = (const float*)d_in[3];
    const float* core2   = (const float*)d_in[4];
    const float* core3   = (const float*)d_in[5];
    float* out = (float*)d_out;

    const size_t need = (size_t)(W_ROWS + U_ROWS) * 16;  // 1.25 MB
    if (ws_size >= need) {
        vuint4* wbf = (vuint4*)d_ws;
        vuint4* ubf = wbf + W_ROWS;

        qt_make_tables<<<NS + U_ROWS / 256, 256, 0, stream>>>(
            core0, core1, core2, core3, wbf, ubf);

        qt_main4<<<MAIN_BLOCKS, 256, 0, stream>>>(
            (const vint4*)states, (const vint4*)actions, wbf, ubf,
            (vfloat4*)out);

        // PROBE: duplicate launch (idempotent — identical outputs).
        // dur_us delta vs 21.3 == steady-state qt_main4 time.
        qt_main4<<<MAIN_BLOCKS, 256, 0, stream>>>(
            (const vint4*)states, (const vint4*)actions, wbf, ubf,
            (vfloat4*)out);
    } else {
        qt_direct<<<QT_B / 256, 256, 0, stream>>>(states, actions, core0, core1,
                                                  core2, core3, out);
    }
}

// Round 11
// 21.724 us; speedup vs baseline: 1.4915x; 1.4915x over previous
//
#include <hip/hip_runtime.h>

// QTLayer via tensor-train composition, bf16 tables, 4 samples/thread:
//   out[b] = core0[s0]·M1(s1)·M2(s2)·c3(a) = w[s0*256+s1] · u[s2*64+a]
// w = core0·core1 (64K rows), u = core2·core3 (16K rows), bf16x8 rows (16 B)
// -> exactly one dwordx4 gather per table per sample (2 scattered lines per
// sample — the structural floor; a 1-gather scheme needs a 2^30-entry table).
//
// FINAL FORM (best-known, 21.3 us). Measured attribution (R10 dup-launch
// probe): qt_main4 ~10-11 us (scattered-request service-rate bound: 2M
// independent 16 B gathers; invariant to ILP x4 / occupancy shape / L1
// bypass sc0; `nt` on gathers hurts by evicting tables from L2),
// make_tables ~2-3 us, fixed graph/launch overhead ~8 us (fusion refuted:
// R6 token-spin races rebuilds on replay, R7 cooperative grid.sync ~120us).
// bf16 tables: absmax 1.82e-12 vs 5.75e-12 threshold (3x margin); halving
// gather requests vs fp32 tables saved 8.6 us (R2->R3).

#define QT_B (1 << 20)
#define NS 256
#define NA 64

#define W_ROWS (NS * NS)   // 65536
#define U_ROWS (NS * NA)   // 16384
#define MAIN_BLOCKS (QT_B / 4 / 256)   // 1024

typedef int          vint4   __attribute__((ext_vector_type(4)));
typedef unsigned int vuint4  __attribute__((ext_vector_type(4)));
typedef float        vfloat4 __attribute__((ext_vector_type(4)));

__device__ __forceinline__ unsigned short f2bf(float x) {
    unsigned int u = __float_as_uint(x);
    unsigned int r = (u + 0x7fffu + ((u >> 16) & 1u)) >> 16;  // RNE
    return (unsigned short)r;
}

__device__ __forceinline__ float bf_lo(unsigned int u) {
    return __uint_as_float(u << 16);
}
__device__ __forceinline__ float bf_hi(unsigned int u) {
    return __uint_as_float(u & 0xffff0000u);
}

__device__ __forceinline__ float dot8bf(vuint4 wv, vuint4 uv) {
    float acc;
    acc = bf_lo(wv.x) * bf_lo(uv.x);
    acc = fmaf(bf_hi(wv.x), bf_hi(uv.x), acc);
    acc = fmaf(bf_lo(wv.y), bf_lo(uv.y), acc);
    acc = fmaf(bf_hi(wv.y), bf_hi(uv.y), acc);
    acc = fmaf(bf_lo(wv.z), bf_lo(uv.z), acc);
    acc = fmaf(bf_hi(wv.z), bf_hi(uv.z), acc);
    acc = fmaf(bf_lo(wv.w), bf_lo(uv.w), acc);
    acc = fmaf(bf_hi(wv.w), bf_hi(uv.w), acc);
    return acc;
}

__device__ __forceinline__ vuint4 pack8bf(const float acc[8]) {
    vuint4 p;
    p.x = (unsigned)f2bf(acc[0]) | ((unsigned)f2bf(acc[1]) << 16);
    p.y = (unsigned)f2bf(acc[2]) | ((unsigned)f2bf(acc[3]) << 16);
    p.z = (unsigned)f2bf(acc[4]) | ((unsigned)f2bf(acc[5]) << 16);
    p.w = (unsigned)f2bf(acc[6]) | ((unsigned)f2bf(acc[7]) << 16);
    return p;
}

__device__ __forceinline__ void build_w_row(
    const float* __restrict__ core0, const float* __restrict__ core1,
    int s0, int s1, vuint4* __restrict__ wbf)
{
    float acc[8] = {0.f, 0.f, 0.f, 0.f, 0.f, 0.f, 0.f, 0.f};
#pragma unroll
    for (int r = 0; r < 8; ++r) {
        const float c = core0[s0 * 8 + r];
        const float* row = core1 + (r * (NS * 8) + s1 * 8);
        const float4 lo = *(const float4*)row;
        const float4 hi = *(const float4*)(row + 4);
        acc[0] = fmaf(c, lo.x, acc[0]);
        acc[1] = fmaf(c, lo.y, acc[1]);
        acc[2] = fmaf(c, lo.z, acc[2]);
        acc[3] = fmaf(c, lo.w, acc[3]);
        acc[4] = fmaf(c, hi.x, acc[4]);
        acc[5] = fmaf(c, hi.y, acc[5]);
        acc[6] = fmaf(c, hi.z, acc[6]);
        acc[7] = fmaf(c, hi.w, acc[7]);
    }
    wbf[s0 * NS + s1] = pack8bf(acc);
}

__device__ __forceinline__ void build_u_row(
    const float* __restrict__ core2, const float* __restrict__ core3,
    int q, vuint4* __restrict__ ubf)
{
    const int s2 = q >> 6;
    const int a  = q & (NA - 1);
    float c3[8];
#pragma unroll
    for (int s = 0; s < 8; ++s) c3[s] = core3[s * NA + a];
    float acc[8];
#pragma unroll
    for (int r = 0; r < 8; ++r) {
        const float* row = core2 + (r * (NS * 8) + s2 * 8);
        const float4 lo = *(const float4*)row;
        const float4 hi = *(const float4*)(row + 4);
        acc[r] = lo.x * c3[0] + lo.y * c3[1] + lo.z * c3[2] + lo.w * c3[3] +
                 hi.x * c3[4] + hi.y * c3[5] + hi.z * c3[6] + hi.w * c3[7];
    }
    ubf[q] = pack8bf(acc);
}

// ---------- precompute: blocks [0,256) build w, [256,320) build u
__global__ __launch_bounds__(256) void qt_make_tables(
    const float* __restrict__ core0,
    const float* __restrict__ core1,
    const float* __restrict__ core2,
    const float* __restrict__ core3,
    vuint4* __restrict__ wbf,
    vuint4* __restrict__ ubf)
{
    const int blk = blockIdx.x;
    if (blk < NS) {
        build_w_row(core0, core1, blk, threadIdx.x, wbf);
    } else {
        build_u_row(core2, core3, (blk - NS) * 256 + threadIdx.x, ubf);
    }
}

// ---------- main: 4 samples/thread, plain gathers (best-known form)
__global__ __launch_bounds__(256) void qt_main4(
    const vint4* __restrict__ states4,
    const vint4* __restrict__ actions4,
    const vuint4* __restrict__ wbf,
    const vuint4* __restrict__ ubf,
    vfloat4* __restrict__ out4)
{
    const int t = blockIdx.x * blockDim.x + threadIdx.x;  // t < B/4

    const vint4 sa = __builtin_nontemporal_load(&states4[3 * t + 0]);
    const vint4 sb = __builtin_nontemporal_load(&states4[3 * t + 1]);
    const vint4 sc = __builtin_nontemporal_load(&states4[3 * t + 2]);
    const vint4 ac = __builtin_nontemporal_load(&actions4[t]);

    // sample 0: (sa.x, sa.y, sa.z, ac.x)
    // sample 1: (sa.w, sb.x, sb.y, ac.y)
    // sample 2: (sb.z, sb.w, sc.x, ac.z)
    // sample 3: (sc.y, sc.z, sc.w, ac.w)
    const vuint4 w0 = wbf[sa.x * NS + sa.y];
    const vuint4 u0 = ubf[sa.z * NA + ac.x];
    const vuint4 w1 = wbf[sa.w * NS + sb.x];
    const vuint4 u1 = ubf[sb.y * NA + ac.y];
    const vuint4 w2 = wbf[sb.z * NS + sb.w];
    const vuint4 u2 = ubf[sc.x * NA + ac.z];
    const vuint4 w3 = wbf[sc.y * NS + sc.z];
    const vuint4 u3 = ubf[sc.w * NA + ac.w];

    vfloat4 o;
    o.x = dot8bf(w0, u0);
    o.y = dot8bf(w1, u1);
    o.z = dot8bf(w2, u2);
    o.w = dot8bf(w3, u3);

    __builtin_nontemporal_store(o, &out4[t]);
}

// ---------- fallback (round-1 kernel) if ws is too small
__global__ __launch_bounds__(256) void qt_direct(
    const int* __restrict__ states,
    const int* __restrict__ actions,
    const float* __restrict__ core0,
    const float* __restrict__ core1,
    const float* __restrict__ core2,
    const float* __restrict__ core3,
    float* __restrict__ out)
{
    const int b = blockIdx.x * blockDim.x + threadIdx.x;
    if (b >= QT_B) return;

    const int s0 = states[3 * b + 0];
    const int s1 = states[3 * b + 1];
    const int s2 = states[3 * b + 2];
    const int a  = actions[b];

    const float4 v0lo = *(const float4*)(core0 + s0 * 8);
    const float4 v0hi = *(const float4*)(core0 + s0 * 8 + 4);
    float v0[8] = {v0lo.x, v0lo.y, v0lo.z, v0lo.w,
                   v0hi.x, v0hi.y, v0hi.z, v0hi.w};

    float v1[8] = {0.f};
#pragma unroll
    for (int r = 0; r < 8; ++r) {
        const float* row = core1 + (r * (NS * 8) + s1 * 8);
        const float4 lo = *(const float4*)row;
        const float4 hi = *(const float4*)(row + 4);
        const float c = v0[r];
        v1[0] = fmaf(c, lo.x, v1[0]); v1[1] = fmaf(c, lo.y, v1[1]);
        v1[2] = fmaf(c, lo.z, v1[2]); v1[3] = fmaf(c, lo.w, v1[3]);
        v1[4] = fmaf(c, hi.x, v1[4]); v1[5] = fmaf(c, hi.y, v1[5]);
        v1[6] = fmaf(c, hi.z, v1[6]); v1[7] = fmaf(c, hi.w, v1[7]);
    }

    float v2[8] = {0.f};
#pragma unroll
    for (int r = 0; r < 8; ++r) {
        const float* row = core2 + (r * (NS * 8) + s2 * 8);
        const float4 lo = *(const float4*)row;
        const float4 hi = *(const float4*)(row + 4);
        const float c = v1[r];
        v2[0] = fmaf(c, lo.x, v2[0]); v2[1] = fmaf(c, lo.y, v2[1]);
        v2[2] = fmaf(c, lo.z, v2[2]); v2[3] = fmaf(c, lo.w, v2[3]);
        v2[4] = fmaf(c, hi.x, v2[4]); v2[5] = fmaf(c, hi.y, v2[5]);
        v2[6] = fmaf(c, hi.z, v2[6]); v2[7] = fmaf(c, hi.w, v2[7]);
    }

    float acc = 0.f;
#pragma unroll
    for (int r = 0; r < 8; ++r) acc = fmaf(v2[r], core3[r * NA + a], acc);
    out[b] = acc;
}

extern "C" void kernel_launch(void* const* d_in, const int* in_sizes, int n_in,
                              void* d_out, int out_size, void* d_ws, size_t ws_size,
                              hipStream_t stream) {
    const int*   states  = (const int*)d_in[0];
    const int*   actions = (const int*)d_in[1];
    const float* core0   = (const float*)d_in[2];
    const float* core1   = (const float*)d_in[3];
    const float* core2   = (const float*)d_in[4];
    const float* core3   = (const float*)d_in[5];
    float* out = (float*)d_out;

    const size_t need = (size_t)(W_ROWS + U_ROWS) * 16;  // 1.25 MB
    if (ws_size >= need) {
        vuint4* wbf = (vuint4*)d_ws;
        vuint4* ubf = wbf + W_ROWS;

        qt_make_tables<<<NS + U_ROWS / 256, 256, 0, stream>>>(
            core0, core1, core2, core3, wbf, ubf);

        qt_main4<<<MAIN_BLOCKS, 256, 0, stream>>>(
            (const vint4*)states, (const vint4*)actions, wbf, ubf,
            (vfloat4*)out);
    } else {
        qt_direct<<<QT_B / 256, 256, 0, stream>>>(states, actions, core0, core1,
                                                  core2, core3, out);
    }
}